// Round 1
// baseline (316.254 us; speedup 1.0000x reference)
//
#include <hip/hip_runtime.h>

typedef unsigned short u16;
typedef float f4 __attribute__((ext_vector_type(4)));
typedef __bf16 b8 __attribute__((ext_vector_type(8)));

__device__ __forceinline__ u16 f2bf(float f) {
  unsigned u = __float_as_uint(f);
  u += 0x7fffu + ((u >> 16) & 1u);
  return (u16)(u >> 16);
}
__device__ __forceinline__ float bf2f(u16 h) {
  return __uint_as_float(((unsigned)h) << 16);
}

// ---------------- convert x (fp32 -> bf16, same layout) ----------------
__global__ void k_convert_x(const float* __restrict__ in, u16* __restrict__ out) {
  int i = (blockIdx.x * 256 + threadIdx.x) * 8;
  float4 a = *(const float4*)(in + i);
  float4 b = *(const float4*)(in + i + 4);
  union { u16 h[8]; uint4 v; } r;
  r.h[0] = f2bf(a.x); r.h[1] = f2bf(a.y); r.h[2] = f2bf(a.z); r.h[3] = f2bf(a.w);
  r.h[4] = f2bf(b.x); r.h[5] = f2bf(b.y); r.h[6] = f2bf(b.z); r.h[7] = f2bf(b.w);
  *(uint4*)(out + i) = r.v;
}

// ------------- transpose+convert weights: w[K][N] fp32 -> wT[N][K] bf16 -------------
__global__ void k_convert_wT(const float* __restrict__ w, u16* __restrict__ wT,
                             int Ncols, int Krows) {
  __shared__ u16 t[64][65];
  int n0 = blockIdx.x * 64, k0 = blockIdx.y * 64;
#pragma unroll
  for (int it = 0; it < 16; ++it) {
    int e = it * 256 + threadIdx.x;
    int r = e >> 6, c = e & 63;
    t[r][c] = f2bf(w[(size_t)(k0 + r) * Ncols + n0 + c]);
  }
  __syncthreads();
#pragma unroll
  for (int it = 0; it < 16; ++it) {
    int e = it * 256 + threadIdx.x;
    int r = e >> 6, c = e & 63;  // r = local n, c = local k
    wT[(size_t)(n0 + r) * Krows + k0 + c] = t[c][r];
  }
}

// ---------------- 128x128 bf16 MFMA GEMM, Bt input ([N][K]) ----------------
// EPI 0: qkv epilogue (scatter to q/k/v [B*H][N][D] bf16, +bias)
// EPI 1: fp32 output [M][Ncols] (+bias)
template <int EPI>
__global__ __launch_bounds__(256, 2) void k_gemm(
    const u16* __restrict__ A, const u16* __restrict__ Bt,
    const float* __restrict__ bias, float* __restrict__ outF,
    u16* __restrict__ oq, u16* __restrict__ ok, u16* __restrict__ ov,
    int K, int Ncols) {
  // stride 40 (=32+8) breaks the 8-way bank conflict of a 64B row stride
  __shared__ u16 lA[128 * 40];
  __shared__ u16 lB[128 * 40];
  const int tid = threadIdx.x;
  const int lane = tid & 63, lrow = lane & 15, lq = lane >> 4;
  const int wave = tid >> 6;
  const int bm = blockIdx.y * 128, bn = blockIdx.x * 128;
  const int wm = (wave >> 1) * 64, wn = (wave & 1) * 64;
  f4 acc[4][4] = {};
  for (int kb = 0; kb < K; kb += 32) {
#pragma unroll
    for (int s = 0; s < 2; ++s) {
      int ch = s * 256 + tid;       // 512 chunks of 16B per tile
      int row = ch >> 2, cc = ch & 3;
      *(uint4*)(lA + row * 40 + cc * 8) =
          *(const uint4*)(A + (size_t)(bm + row) * K + kb + cc * 8);
      *(uint4*)(lB + row * 40 + cc * 8) =
          *(const uint4*)(Bt + (size_t)(bn + row) * K + kb + cc * 8);
    }
    __syncthreads();
    b8 af[4], bf[4];
#pragma unroll
    for (int i = 0; i < 4; ++i)
      af[i] = *(const b8*)(lA + (wm + i * 16 + lrow) * 40 + lq * 8);
#pragma unroll
    for (int j = 0; j < 4; ++j)
      bf[j] = *(const b8*)(lB + (wn + j * 16 + lrow) * 40 + lq * 8);
#pragma unroll
    for (int i = 0; i < 4; ++i)
#pragma unroll
      for (int j = 0; j < 4; ++j)
        acc[i][j] = __builtin_amdgcn_mfma_f32_16x16x32_bf16(af[i], bf[j], acc[i][j], 0, 0, 0);
    __syncthreads();
  }
#pragma unroll
  for (int i = 0; i < 4; ++i)
#pragma unroll
    for (int j = 0; j < 4; ++j) {
      int n = bn + wn + j * 16 + lrow;
      float bv = bias[n];
#pragma unroll
      for (int r = 0; r < 4; ++r) {
        int m = bm + wm + i * 16 + lq * 4 + r;   // C/D layout: row=quad*4+r, col=lane&15
        float val = acc[i][j][r] + bv;
        if (EPI == 1) {
          outF[(size_t)m * Ncols + n] = val;
        } else {
          int which = n >> 10, h = (n >> 6) & 15, d = n & 63;
          int bb = m >> 11, ns = m & 2047;
          u16* dst = which == 0 ? oq : (which == 1 ? ok : ov);
          dst[((size_t)(bb * 16 + h) * 2048 + ns) * 64 + d] = f2bf(val);
        }
      }
    }
}

// ---------------- per-head RMSNorm on q,k (row = D = 64 = one wave) ----------------
__global__ void k_rmsnorm(u16* __restrict__ qb, u16* __restrict__ kb,
                          const float* __restrict__ qw, const float* __restrict__ kw) {
  int row = blockIdx.x * 4 + (threadIdx.x >> 6);
  int lane = threadIdx.x & 63;
  const int half = 32 * 2048;  // B*H*N
  u16* buf; const float* w; int r;
  if (row < half) { buf = qb; w = qw; r = row; }
  else            { buf = kb; w = kw; r = row - half; }
  size_t idx = (size_t)r * 64 + lane;
  float v = bf2f(buf[idx]);
  float s = v * v;
#pragma unroll
  for (int o = 32; o > 0; o >>= 1) s += __shfl_xor(s, o, 64);
  float sc = rsqrtf(s * (1.0f / 64.0f) + 1e-6f);
  buf[idx] = f2bf(v * sc * w[lane]);
}

// ---------------- V transpose: [BH][N][D] -> [BH][D][N] ----------------
__global__ void k_transpose_v(const u16* __restrict__ v, u16* __restrict__ vt) {
  __shared__ u16 t[64][65];
  int bh = blockIdx.y, n0 = blockIdx.x * 64;
#pragma unroll
  for (int it = 0; it < 16; ++it) {
    int e = it * 256 + threadIdx.x;
    int r = e >> 6, c = e & 63;
    t[r][c] = v[((size_t)bh * 2048 + n0 + r) * 64 + c];
  }
  __syncthreads();
#pragma unroll
  for (int it = 0; it < 16; ++it) {
    int e = it * 256 + threadIdx.x;
    int r = e >> 6, c = e & 63;  // r = d, c = local n
    vt[((size_t)bh * 64 + r) * 2048 + n0 + c] = t[c][r];
  }
}

// ---------------- flash attention: Q-tile 128 (4 waves x 32 rows), K-tile 64 ----------------
__global__ __launch_bounds__(256, 2) void k_attn(
    const u16* __restrict__ qb, const u16* __restrict__ kb,
    const u16* __restrict__ vt, u16* __restrict__ ao) {
  __shared__ u16 lK[64 * 80];       // [key n][head-dim kk], stride 80
  __shared__ u16 lV[64 * 80];       // [d][key k], stride 80
  __shared__ u16 lP[4][32 * 80];    // per-wave P, [m][k], stride 80
  const int bh = blockIdx.y;
  const int q0 = blockIdx.x * 128;
  const int tid = threadIdx.x, wave = tid >> 6, lane = tid & 63;
  const int lrow = lane & 15, lq = lane >> 4;
  const int wq = wave * 32;
  const float cs = 0.125f * 1.44269504088896340736f;  // scale * log2(e)

  // Q fragments live in registers across the whole K loop (A-layout: m=lane&15, k=quad*8+j)
  b8 qf[2][2];
#pragma unroll
  for (int tm = 0; tm < 2; ++tm)
#pragma unroll
    for (int ks = 0; ks < 2; ++ks)
      qf[tm][ks] = *(const b8*)(qb + ((size_t)bh * 2048 + q0 + wq + tm * 16 + lrow) * 64 +
                                ks * 32 + lq * 8);

  float mr[2][4], lr[2][4];
  f4 o[2][4] = {};
#pragma unroll
  for (int tm = 0; tm < 2; ++tm)
#pragma unroll
    for (int r = 0; r < 4; ++r) { mr[tm][r] = -3.0e38f; lr[tm][r] = 0.f; }

  for (int kt = 0; kt < 2048; kt += 64) {
#pragma unroll
    for (int s = 0; s < 2; ++s) {
      int ch = s * 256 + tid;   // 512 chunks of 16B (K tile + V tile)
      int row = ch >> 3, cc = ch & 7;
      *(uint4*)(lK + row * 80 + cc * 8) =
          *(const uint4*)(kb + ((size_t)bh * 2048 + kt + row) * 64 + cc * 8);
      *(uint4*)(lV + row * 80 + cc * 8) =
          *(const uint4*)(vt + ((size_t)bh * 64 + row) * 2048 + kt + cc * 8);
    }
    __syncthreads();

    // S = Q K^T  (2 m-tiles x 4 n-tiles, K=64 via 2 MFMA steps)
    f4 s4[2][4] = {};
#pragma unroll
    for (int ks = 0; ks < 2; ++ks)
#pragma unroll
      for (int tn = 0; tn < 4; ++tn) {
        b8 kf = *(const b8*)(lK + (tn * 16 + lrow) * 80 + ks * 32 + lq * 8);
#pragma unroll
        for (int tm = 0; tm < 2; ++tm)
          s4[tm][tn] = __builtin_amdgcn_mfma_f32_16x16x32_bf16(qf[tm][ks], kf, s4[tm][tn], 0, 0, 0);
      }

    // online softmax per row (row = tm*16 + quad*4 + r; 16 col-lanes reduce via shfl_xor)
#pragma unroll
    for (int tm = 0; tm < 2; ++tm)
#pragma unroll
      for (int r = 0; r < 4; ++r) {
        float mx = fmaxf(fmaxf(s4[tm][0][r], s4[tm][1][r]), fmaxf(s4[tm][2][r], s4[tm][3][r]));
#pragma unroll
        for (int off = 1; off < 16; off <<= 1) mx = fmaxf(mx, __shfl_xor(mx, off, 64));
        float mnew = fmaxf(mr[tm][r], mx);
        float alpha = exp2f((mr[tm][r] - mnew) * cs);
        mr[tm][r] = mnew;
        float ps = 0.f;
#pragma unroll
        for (int tn = 0; tn < 4; ++tn) {
          float p = exp2f((s4[tm][tn][r] - mnew) * cs);
          s4[tm][tn][r] = p;
          ps += p;
        }
#pragma unroll
        for (int off = 1; off < 16; off <<= 1) ps += __shfl_xor(ps, off, 64);
        lr[tm][r] = lr[tm][r] * alpha + ps;
#pragma unroll
        for (int tn = 0; tn < 4; ++tn) o[tm][tn][r] *= alpha;
      }

    // P: C-layout regs -> LDS -> A-layout frags (verified m120 transform)
    u16* pw = lP[wave];
#pragma unroll
    for (int tm = 0; tm < 2; ++tm)
#pragma unroll
      for (int tn = 0; tn < 4; ++tn)
#pragma unroll
        for (int r = 0; r < 4; ++r)
          pw[(tm * 16 + lq * 4 + r) * 80 + tn * 16 + lrow] = f2bf(s4[tm][tn][r]);

    // O += P V  (2 m-tiles x 4 d-tiles, K=64 via 2 steps)
#pragma unroll
    for (int kv = 0; kv < 2; ++kv) {
      b8 pf[2];
#pragma unroll
      for (int tm = 0; tm < 2; ++tm)
        pf[tm] = *(const b8*)(pw + (tm * 16 + lrow) * 80 + kv * 32 + lq * 8);
#pragma unroll
      for (int tn = 0; tn < 4; ++tn) {
        b8 vf = *(const b8*)(lV + (tn * 16 + lrow) * 80 + kv * 32 + lq * 8);
#pragma unroll
        for (int tm = 0; tm < 2; ++tm)
          o[tm][tn] = __builtin_amdgcn_mfma_f32_16x16x32_bf16(pf[tm], vf, o[tm][tn], 0, 0, 0);
      }
    }
    __syncthreads();
  }

  const int bb = bh >> 4, h = bh & 15;
#pragma unroll
  for (int tm = 0; tm < 2; ++tm)
#pragma unroll
    for (int tn = 0; tn < 4; ++tn)
#pragma unroll
      for (int r = 0; r < 4; ++r) {
        int m = q0 + wq + tm * 16 + lq * 4 + r;
        int dv = tn * 16 + lrow;
        float val = o[tm][tn][r] / lr[tm][r];
        ao[((size_t)bb * 2048 + m) * 1024 + h * 64 + dv] = f2bf(val);
      }
}

extern "C" void kernel_launch(void* const* d_in, const int* in_sizes, int n_in,
                              void* d_out, int out_size, void* d_ws, size_t ws_size,
                              hipStream_t stream) {
  const float* x      = (const float*)d_in[0];
  const float* w_qkv  = (const float*)d_in[1];
  const float* b_qkv  = (const float*)d_in[2];
  const float* q_w    = (const float*)d_in[3];
  const float* k_w    = (const float*)d_in[4];
  const float* w_proj = (const float*)d_in[5];
  const float* b_proj = (const float*)d_in[6];
  float* out = (float*)d_out;

  // ws layout (u16 elems): xb | wqkT | wpjT | qb | kb | vb | vtb   (ao reuses xb) = 48 MB
  u16* xb   = (u16*)d_ws;
  u16* wqkT = xb + 4194304;
  u16* wpjT = wqkT + 3145728;
  u16* qb   = wpjT + 1048576;
  u16* kb   = qb + 4194304;
  u16* vb   = kb + 4194304;
  u16* vtb  = vb + 4194304;
  u16* ao   = xb;  // x no longer needed after the QKV GEMM

  k_convert_x<<<2048, 256, 0, stream>>>(x, xb);
  k_convert_wT<<<dim3(48, 16), 256, 0, stream>>>(w_qkv, wqkT, 3072, 1024);
  k_convert_wT<<<dim3(16, 16), 256, 0, stream>>>(w_proj, wpjT, 1024, 1024);
  k_gemm<0><<<dim3(24, 32), 256, 0, stream>>>(xb, wqkT, b_qkv, nullptr, qb, kb, vb, 1024, 3072);
  k_rmsnorm<<<32768, 256, 0, stream>>>(qb, kb, q_w, k_w);
  k_transpose_v<<<dim3(32, 32), 256, 0, stream>>>(vb, vtb);
  k_attn<<<dim3(16, 32), 256, 0, stream>>>(qb, kb, vtb, ao);
  k_gemm<1><<<dim3(8, 32), 256, 0, stream>>>(ao, wpjT, b_proj, out, nullptr, nullptr, nullptr, 1024, 1024);
}

// Round 2
// 265.350 us; speedup vs baseline: 1.1918x; 1.1918x over previous
//
#include <hip/hip_runtime.h>

typedef unsigned short u16;
typedef float f4 __attribute__((ext_vector_type(4)));
typedef __bf16 b8 __attribute__((ext_vector_type(8)));
typedef _Float16 h4 __attribute__((ext_vector_type(4)));

__device__ __forceinline__ u16 f2bf(float f) {
  unsigned u = __float_as_uint(f);
  u += 0x7fffu + ((u >> 16) & 1u);
  return (u16)(u >> 16);
}
__device__ __forceinline__ float bf2f(u16 h) {
  return __uint_as_float(((unsigned)h) << 16);
}
__device__ __forceinline__ f4 max4(f4 a, f4 b) {
  f4 r;
  r[0] = fmaxf(a[0], b[0]); r[1] = fmaxf(a[1], b[1]);
  r[2] = fmaxf(a[2], b[2]); r[3] = fmaxf(a[3], b[3]);
  return r;
}

// ---------------- convert x (fp32 -> bf16, same layout) ----------------
__global__ void k_convert_x(const float* __restrict__ in, u16* __restrict__ out) {
  int i = (blockIdx.x * 256 + threadIdx.x) * 8;
  float4 a = *(const float4*)(in + i);
  float4 b = *(const float4*)(in + i + 4);
  union { u16 h[8]; uint4 v; } r;
  r.h[0] = f2bf(a.x); r.h[1] = f2bf(a.y); r.h[2] = f2bf(a.z); r.h[3] = f2bf(a.w);
  r.h[4] = f2bf(b.x); r.h[5] = f2bf(b.y); r.h[6] = f2bf(b.z); r.h[7] = f2bf(b.w);
  *(uint4*)(out + i) = r.v;
}

// ------------- transpose+convert weights: w[K][N] fp32 -> wT[N][K] bf16 -------------
__global__ void k_convert_wT(const float* __restrict__ w, u16* __restrict__ wT,
                             int Ncols, int Krows) {
  __shared__ u16 t[64][65];
  int n0 = blockIdx.x * 64, k0 = blockIdx.y * 64;
#pragma unroll
  for (int it = 0; it < 16; ++it) {
    int e = it * 256 + threadIdx.x;
    int r = e >> 6, c = e & 63;
    t[r][c] = f2bf(w[(size_t)(k0 + r) * Ncols + n0 + c]);
  }
  __syncthreads();
#pragma unroll
  for (int it = 0; it < 16; ++it) {
    int e = it * 256 + threadIdx.x;
    int r = e >> 6, c = e & 63;  // r = local n, c = local k
    wT[(size_t)(n0 + r) * Krows + k0 + c] = t[c][r];
  }
}

// ---------------- 128x128 bf16 MFMA GEMM, Bt input ([N][K]) ----------------
template <int EPI>
__global__ __launch_bounds__(256, 2) void k_gemm(
    const u16* __restrict__ A, const u16* __restrict__ Bt,
    const float* __restrict__ bias, float* __restrict__ outF,
    u16* __restrict__ oq, u16* __restrict__ ok, u16* __restrict__ ov,
    int K, int Ncols) {
  __shared__ u16 lA[128 * 40];
  __shared__ u16 lB[128 * 40];
  const int tid = threadIdx.x;
  const int lane = tid & 63, lrow = lane & 15, lq = lane >> 4;
  const int wave = tid >> 6;
  const int bm = blockIdx.y * 128, bn = blockIdx.x * 128;
  const int wm = (wave >> 1) * 64, wn = (wave & 1) * 64;
  f4 acc[4][4] = {};
  for (int kb = 0; kb < K; kb += 32) {
#pragma unroll
    for (int s = 0; s < 2; ++s) {
      int ch = s * 256 + tid;
      int row = ch >> 2, cc = ch & 3;
      *(uint4*)(lA + row * 40 + cc * 8) =
          *(const uint4*)(A + (size_t)(bm + row) * K + kb + cc * 8);
      *(uint4*)(lB + row * 40 + cc * 8) =
          *(const uint4*)(Bt + (size_t)(bn + row) * K + kb + cc * 8);
    }
    __syncthreads();
    b8 af[4], bf[4];
#pragma unroll
    for (int i = 0; i < 4; ++i)
      af[i] = *(const b8*)(lA + (wm + i * 16 + lrow) * 40 + lq * 8);
#pragma unroll
    for (int j = 0; j < 4; ++j)
      bf[j] = *(const b8*)(lB + (wn + j * 16 + lrow) * 40 + lq * 8);
#pragma unroll
    for (int i = 0; i < 4; ++i)
#pragma unroll
      for (int j = 0; j < 4; ++j)
        acc[i][j] = __builtin_amdgcn_mfma_f32_16x16x32_bf16(af[i], bf[j], acc[i][j], 0, 0, 0);
    __syncthreads();
  }
#pragma unroll
  for (int i = 0; i < 4; ++i)
#pragma unroll
    for (int j = 0; j < 4; ++j) {
      int n = bn + wn + j * 16 + lrow;
      float bv = bias[n];
#pragma unroll
      for (int r = 0; r < 4; ++r) {
        int m = bm + wm + i * 16 + lq * 4 + r;
        float val = acc[i][j][r] + bv;
        if (EPI == 1) {
          outF[(size_t)m * Ncols + n] = val;
        } else {
          int which = n >> 10, h = (n >> 6) & 15, d = n & 63;
          int bb = m >> 11, ns = m & 2047;
          u16* dst = which == 0 ? oq : (which == 1 ? ok : ov);
          dst[((size_t)(bb * 16 + h) * 2048 + ns) * 64 + d] = f2bf(val);
        }
      }
    }
}

// ------------- per-head RMSNorm on q,k (vectorized: 16 lanes x 4 elems per row) -------------
// q rows additionally get the attention scale * log2(e) folded in.
__global__ void k_rmsnorm(u16* __restrict__ qb, u16* __restrict__ kb,
                          const float* __restrict__ qw, const float* __restrict__ kw) {
  const float CS = 0.125f * 1.44269504088896340736f;
  int wave = threadIdx.x >> 6, lane = threadIdx.x & 63;
  int row = blockIdx.x * 16 + wave * 4 + (lane >> 4);
  int c4 = (lane & 15) * 4;
  const int half = 65536;  // B*H*N
  u16* buf; const float* w; float extra;
  if (row < half) { buf = qb; w = qw; extra = CS; }
  else            { buf = kb; w = kw; extra = 1.0f; row -= half; }
  u16* p = buf + (size_t)row * 64 + c4;
  union { u16 h[4]; uint2 v; } in, outv;
  in.v = *(const uint2*)p;
  float x0 = bf2f(in.h[0]), x1 = bf2f(in.h[1]), x2 = bf2f(in.h[2]), x3 = bf2f(in.h[3]);
  float s = x0 * x0 + x1 * x1 + x2 * x2 + x3 * x3;
#pragma unroll
  for (int o = 8; o > 0; o >>= 1) s += __shfl_xor(s, o, 64);
  float sc = rsqrtf(s * (1.0f / 64.0f) + 1e-6f) * extra;
  float4 wv = *(const float4*)(w + c4);
  outv.h[0] = f2bf(x0 * sc * wv.x); outv.h[1] = f2bf(x1 * sc * wv.y);
  outv.h[2] = f2bf(x2 * sc * wv.z); outv.h[3] = f2bf(x3 * sc * wv.w);
  *(uint2*)p = outv.v;
}

// ---------------- V transpose + bf16->f16: [BH][N][D] -> [BH][D][N] f16 ----------------
__global__ void k_transpose_v(const u16* __restrict__ v, u16* __restrict__ vtb) {
  __shared__ u16 t[64][65];
  int bh = blockIdx.y, n0 = blockIdx.x * 64;
#pragma unroll
  for (int it = 0; it < 16; ++it) {
    int e = it * 256 + threadIdx.x;
    int r = e >> 6, c = e & 63;
    t[r][c] = v[((size_t)bh * 2048 + n0 + r) * 64 + c];
  }
  __syncthreads();
#pragma unroll
  for (int it = 0; it < 16; ++it) {
    int e = it * 256 + threadIdx.x;
    int r = e >> 6, c = e & 63;  // r = d, c = local n
    union { _Float16 h; u16 u; } cv;
    cv.h = (_Float16)bf2f(t[c][r]);
    vtb[((size_t)bh * 64 + r) * 2048 + n0 + c] = cv.u;
  }
}

// ---------------- flash attention, S^T orientation ----------------
// Q-tile 128 (4 waves x 32 q), K-tile 64. ST = K·Q^T in C-layout => per-q softmax
// reduces in-register + 2 shuffles; ST C-layout == B-operand of 16x16x16 MFMA,
// so PV (O^T = V^T·P^T) needs NO LDS round-trip for P.
__global__ __launch_bounds__(256, 4) void k_attn(
    const u16* __restrict__ qb, const u16* __restrict__ kb,
    const u16* __restrict__ vt, u16* __restrict__ ao) {
  __shared__ u16 lK[64 * 72];   // [key][d], stride 72 (36 dw: 2-way banks, free)
  __shared__ u16 lV[64 * 72];   // [d][key] f16, stride 72
  const int bh = blockIdx.y;
  const int q0 = blockIdx.x * 128;
  const int tid = threadIdx.x, wave = tid >> 6, lane = tid & 63;
  const int lrow = lane & 15, lq = lane >> 4;
  const int wq = wave * 32;

  // Q fragments (B-operand layout: n=q=lane&15, k=d=quad*8+j); q pre-scaled by cs in rmsnorm
  b8 qf[2][2];
#pragma unroll
  for (int qt = 0; qt < 2; ++qt)
#pragma unroll
    for (int ks = 0; ks < 2; ++ks)
      qf[qt][ks] = *(const b8*)(qb + ((size_t)bh * 2048 + q0 + wq + qt * 16 + lrow) * 64 +
                                ks * 32 + lq * 8);

  float mr[2] = {-3.0e38f, -3.0e38f}, lr[2] = {0.f, 0.f};
  f4 o[4][2] = {};  // O^T tiles: [dt][qt], row=d=quad*4+r, col=q=lane&15

  const u16* kbase = kb + (size_t)bh * 2048 * 64;
  const u16* vbase = vt + (size_t)bh * 64 * 2048;

  for (int kt0 = 0; kt0 < 2048; kt0 += 64) {
#pragma unroll
    for (int s = 0; s < 2; ++s) {
      int ch = s * 256 + tid;  // 512 chunks of 16B per tile
      int row = ch >> 3, cc = ch & 7;
      *(uint4*)(lK + row * 72 + cc * 8) =
          *(const uint4*)(kbase + (size_t)(kt0 + row) * 64 + cc * 8);
      *(uint4*)(lV + row * 72 + cc * 8) =
          *(const uint4*)(vbase + (size_t)row * 2048 + kt0 + cc * 8);
    }
    __syncthreads();

    // ST = K·Q^T: st[kt][qt], row=key=quad*4+r, col=q=lane&15
    f4 st[4][2] = {};
#pragma unroll
    for (int ks = 0; ks < 2; ++ks)
#pragma unroll
      for (int kt = 0; kt < 4; ++kt) {
        b8 kf = *(const b8*)(lK + (kt * 16 + lrow) * 72 + ks * 32 + lq * 8);
#pragma unroll
        for (int qt = 0; qt < 2; ++qt)
          st[kt][qt] = __builtin_amdgcn_mfma_f32_16x16x32_bf16(kf, qf[qt][ks], st[kt][qt], 0, 0, 0);
      }

    // online softmax: per-q stats live along registers+quads (2 shuffles per qt)
    h4 pf[4][2];
#pragma unroll
    for (int qt = 0; qt < 2; ++qt) {
      f4 m4 = max4(max4(st[0][qt], st[1][qt]), max4(st[2][qt], st[3][qt]));
      float mx = fmaxf(fmaxf(m4[0], m4[1]), fmaxf(m4[2], m4[3]));
      mx = fmaxf(mx, __shfl_xor(mx, 16, 64));
      mx = fmaxf(mx, __shfl_xor(mx, 32, 64));
      float mnew = fmaxf(mr[qt], mx);
      float a = exp2f(mr[qt] - mnew);
      mr[qt] = mnew;
      f4 psum = {};
#pragma unroll
      for (int kt = 0; kt < 4; ++kt) {
        f4 pv;
#pragma unroll
        for (int r = 0; r < 4; ++r) pv[r] = exp2f(st[kt][qt][r] - mnew);
        pf[kt][qt][0] = (_Float16)pv[0]; pf[kt][qt][1] = (_Float16)pv[1];
        pf[kt][qt][2] = (_Float16)pv[2]; pf[kt][qt][3] = (_Float16)pv[3];
        psum += pv;
      }
      float ps = psum[0] + psum[1] + psum[2] + psum[3];
      ps += __shfl_xor(ps, 16, 64);
      ps += __shfl_xor(ps, 32, 64);
      lr[qt] = lr[qt] * a + ps;
#pragma unroll
      for (int dt = 0; dt < 4; ++dt) o[dt][qt] *= a;
    }

    // O^T += V^T · P^T  (K=16 MFMA; P^T frags are st's C-layout regs, no LDS)
#pragma unroll
    for (int kt = 0; kt < 4; ++kt)
#pragma unroll
      for (int dt = 0; dt < 4; ++dt) {
        h4 va = *(const h4*)(lV + (dt * 16 + lrow) * 72 + kt * 16 + lq * 4);
#pragma unroll
        for (int qt = 0; qt < 2; ++qt)
          o[dt][qt] = __builtin_amdgcn_mfma_f32_16x16x16f16(va, pf[kt][qt], o[dt][qt], 0, 0, 0);
      }
    __syncthreads();
  }

  const int bb = bh >> 4, h = bh & 15;
#pragma unroll
  for (int qt = 0; qt < 2; ++qt) {
    float inv = 1.0f / lr[qt];
    int q = q0 + wq + qt * 16 + lrow;
#pragma unroll
    for (int dt = 0; dt < 4; ++dt) {
      union { u16 h2[4]; uint2 v; } r;
#pragma unroll
      for (int rr = 0; rr < 4; ++rr) r.h2[rr] = f2bf(o[dt][qt][rr] * inv);
      *(uint2*)(ao + ((size_t)bb * 2048 + q) * 1024 + h * 64 + dt * 16 + lq * 4) = r.v;
    }
  }
}

extern "C" void kernel_launch(void* const* d_in, const int* in_sizes, int n_in,
                              void* d_out, int out_size, void* d_ws, size_t ws_size,
                              hipStream_t stream) {
  const float* x      = (const float*)d_in[0];
  const float* w_qkv  = (const float*)d_in[1];
  const float* b_qkv  = (const float*)d_in[2];
  const float* q_w    = (const float*)d_in[3];
  const float* k_w    = (const float*)d_in[4];
  const float* w_proj = (const float*)d_in[5];
  const float* b_proj = (const float*)d_in[6];
  float* out = (float*)d_out;

  u16* xb   = (u16*)d_ws;
  u16* wqkT = xb + 4194304;
  u16* wpjT = wqkT + 3145728;
  u16* qb   = wpjT + 1048576;
  u16* kb   = qb + 4194304;
  u16* vb   = kb + 4194304;
  u16* vtb  = vb + 4194304;
  u16* ao   = xb;  // x no longer needed after the QKV GEMM

  k_convert_x<<<2048, 256, 0, stream>>>(x, xb);
  k_convert_wT<<<dim3(48, 16), 256, 0, stream>>>(w_qkv, wqkT, 3072, 1024);
  k_convert_wT<<<dim3(16, 16), 256, 0, stream>>>(w_proj, wpjT, 1024, 1024);
  k_gemm<0><<<dim3(24, 32), 256, 0, stream>>>(xb, wqkT, b_qkv, nullptr, qb, kb, vb, 1024, 3072);
  k_rmsnorm<<<8192, 256, 0, stream>>>(qb, kb, q_w, k_w);
  k_transpose_v<<<dim3(32, 32), 256, 0, stream>>>(vb, vtb);
  k_attn<<<dim3(16, 32), 256, 0, stream>>>(qb, kb, vtb, ao);
  k_gemm<1><<<dim3(8, 32), 256, 0, stream>>>(ao, wpjT, b_proj, out, nullptr, nullptr, nullptr, 1024, 1024);
}

// Round 4
// 225.736 us; speedup vs baseline: 1.4010x; 1.1755x over previous
//
#include <hip/hip_runtime.h>

typedef unsigned short u16;
typedef unsigned int u32;
typedef float f4 __attribute__((ext_vector_type(4)));
typedef __bf16 b8 __attribute__((ext_vector_type(8)));
typedef _Float16 h4 __attribute__((ext_vector_type(4)));

typedef const __attribute__((address_space(1))) u32 gu32;
typedef __attribute__((address_space(3))) u32 lu32;

__device__ __forceinline__ void gll16(const void* g, void* l) {
  // async global->LDS, 16B/lane; LDS dest = wave-uniform base + lane*16
  __builtin_amdgcn_global_load_lds((gu32*)g, (lu32*)l, 16, 0, 0);
}

__device__ __forceinline__ u16 f2bf(float f) {
  unsigned u = __float_as_uint(f);
  u += 0x7fffu + ((u >> 16) & 1u);
  return (u16)(u >> 16);
}
__device__ __forceinline__ float bf2f(u16 h) {
  return __uint_as_float(((unsigned)h) << 16);
}
__device__ __forceinline__ f4 max4(f4 a, f4 b) {
  f4 r;
  r[0] = fmaxf(a[0], b[0]); r[1] = fmaxf(a[1], b[1]);
  r[2] = fmaxf(a[2], b[2]); r[3] = fmaxf(a[3], b[3]);
  return r;
}

// ---------------- convert x (fp32 -> bf16, same layout) ----------------
__global__ void k_convert_x(const float* __restrict__ in, u16* __restrict__ out) {
  int i = (blockIdx.x * 256 + threadIdx.x) * 8;
  float4 a = *(const float4*)(in + i);
  float4 b = *(const float4*)(in + i + 4);
  union { u16 h[8]; uint4 v; } r;
  r.h[0] = f2bf(a.x); r.h[1] = f2bf(a.y); r.h[2] = f2bf(a.z); r.h[3] = f2bf(a.w);
  r.h[4] = f2bf(b.x); r.h[5] = f2bf(b.y); r.h[6] = f2bf(b.z); r.h[7] = f2bf(b.w);
  *(uint4*)(out + i) = r.v;
}

// ------------- transpose+convert weights: w[K][N] fp32 -> wT[N][K] bf16 -------------
__global__ void k_convert_wT(const float* __restrict__ w, u16* __restrict__ wT,
                             int Ncols, int Krows) {
  __shared__ u16 t[64][65];
  int n0 = blockIdx.x * 64, k0 = blockIdx.y * 64;
#pragma unroll
  for (int it = 0; it < 16; ++it) {
    int e = it * 256 + threadIdx.x;
    int r = e >> 6, c = e & 63;
    t[r][c] = f2bf(w[(size_t)(k0 + r) * Ncols + n0 + c]);
  }
  __syncthreads();
#pragma unroll
  for (int it = 0; it < 16; ++it) {
    int e = it * 256 + threadIdx.x;
    int r = e >> 6, c = e & 63;  // r = local n, c = local k
    wT[(size_t)(n0 + r) * Krows + k0 + c] = t[c][r];
  }
}

// ---------------- 128x128 bf16 MFMA GEMM (m97 structure: global_load_lds) ----------------
// EPI 0: QKV epilogue — fused per-head RMSNorm on q/k (+ attention scale on q),
//        scatter q/k -> [BH][N][D] bf16, V -> transposed [BH][D][N] f16.
// EPI 1: fp32 output [M][Ncols] (+bias)
template <int EPI>
__global__ __launch_bounds__(256, 3) void k_gemm(
    const u16* __restrict__ A, const u16* __restrict__ Bt,
    const float* __restrict__ bias, float* __restrict__ outF,
    u16* __restrict__ oq, u16* __restrict__ ok, u16* __restrict__ ov,
    const float* __restrict__ qw, const float* __restrict__ kw,
    int K, int Ncols) {
  __shared__ u16 lA[128 * 32];   // unpadded 64B rows (required by global_load_lds)
  __shared__ u16 lB[128 * 32];
  const int tid = threadIdx.x;
  const int lane = tid & 63, lrow = lane & 15, lq = lane >> 4;
  const int wave = tid >> 6;
  const int bm = blockIdx.y * 128, bn = blockIdx.x * 128;
  const int wm = (wave >> 1) * 64, wn = (wave & 1) * 64;
  f4 acc[4][4] = {};
  for (int kb = 0; kb < K; kb += 32) {
#pragma unroll
    for (int s = 0; s < 2; ++s) {
      int cb = s * 256 + wave * 64;          // wave-uniform chunk base
      int ch = cb + lane;                    // 16B chunk id (4 per 32-elem row)
      int row = ch >> 2, ko = (ch & 3) * 8;
      gll16(A + (size_t)(bm + row) * K + kb + ko, lA + cb * 8);
      gll16(Bt + (size_t)(bn + row) * K + kb + ko, lB + cb * 8);
    }
    __syncthreads();
    b8 af[4], bf[4];
#pragma unroll
    for (int i = 0; i < 4; ++i)
      af[i] = *(const b8*)(lA + (wm + i * 16 + lrow) * 32 + lq * 8);
#pragma unroll
    for (int j = 0; j < 4; ++j)
      bf[j] = *(const b8*)(lB + (wn + j * 16 + lrow) * 32 + lq * 8);
#pragma unroll
    for (int i = 0; i < 4; ++i)
#pragma unroll
      for (int j = 0; j < 4; ++j)
        acc[i][j] = __builtin_amdgcn_mfma_f32_16x16x32_bf16(af[i], bf[j], acc[i][j], 0, 0, 0);
    __syncthreads();
  }

  float bv[4];
#pragma unroll
  for (int j = 0; j < 4; ++j) bv[j] = bias[bn + wn + j * 16 + lrow];

  if (EPI == 1) {
#pragma unroll
    for (int i = 0; i < 4; ++i)
#pragma unroll
      for (int j = 0; j < 4; ++j) {
        int n = bn + wn + j * 16 + lrow;
#pragma unroll
        for (int r = 0; r < 4; ++r) {
          int m = bm + wm + i * 16 + lq * 4 + r;
          outF[(size_t)m * Ncols + n] = acc[i][j][r] + bv[j];
        }
      }
  } else {
    const float CS = 0.125f * 1.44269504088896340736f;  // scale * log2(e), folded into q
    const int n0w = bn + wn;                 // 64-aligned: one head's D-range per wave
    const int sec = n0w >> 10;               // 0=q, 1=k, 2=v (wave-uniform)
    const int h = (n0w >> 6) & 15;
#pragma unroll
    for (int i = 0; i < 4; ++i) {
      float v[4][4];  // [j][r]
#pragma unroll
      for (int j = 0; j < 4; ++j)
#pragma unroll
        for (int r = 0; r < 4; ++r) v[j][r] = acc[i][j][r] + bv[j];
      if (sec < 2) {
        u16* dst = sec == 0 ? oq : ok;
        const float* w = sec == 0 ? qw : kw;
        float ex = sec == 0 ? CS : 1.0f;
#pragma unroll
        for (int r = 0; r < 4; ++r) {
          float ss = v[0][r] * v[0][r] + v[1][r] * v[1][r] +
                     v[2][r] * v[2][r] + v[3][r] * v[3][r];
          // row m = wm+i*16+lq*4+r lives on the 16 lanes of quad lq: reduce lrow bits
          ss += __shfl_xor(ss, 1, 64); ss += __shfl_xor(ss, 2, 64);
          ss += __shfl_xor(ss, 4, 64); ss += __shfl_xor(ss, 8, 64);
          float sc = rsqrtf(ss * (1.0f / 64.0f) + 1e-6f) * ex;
          int m = bm + wm + i * 16 + lq * 4 + r;
          int bb = m >> 11, ns = m & 2047;
          u16* rowp = dst + ((size_t)(bb * 16 + h) * 2048 + ns) * 64;
#pragma unroll
          for (int j = 0; j < 4; ++j) {
            int d = j * 16 + lrow;
            rowp[d] = f2bf(v[j][r] * sc * w[d]);
          }
        }
      } else {
        // V: write transposed [BH][D][N] as f16, 4 consecutive ns per store
        int m0 = bm + wm + i * 16 + lq * 4;
        int bb = m0 >> 11, ns = m0 & 2047;
#pragma unroll
        for (int j = 0; j < 4; ++j) {
          int d = j * 16 + lrow;
          union { _Float16 hh[4]; uint2 u; } pk;
#pragma unroll
          for (int r = 0; r < 4; ++r) pk.hh[r] = (_Float16)v[j][r];
          *(uint2*)(ov + ((size_t)(bb * 16 + h) * 64 + d) * 2048 + ns) = pk.u;
        }
      }
    }
  }
}

// ---------------- flash attention, S^T orientation ----------------
// 512 threads = 8 waves; Q-tile 128 (16 q per wave), K-tile 128.
// ST = K·Q^T in C-layout => per-q softmax reduces in-register + 2 shuffles;
// ST C-layout == B-operand of 16x16x16 MFMA => PV needs no LDS round-trip for P.
__global__ __launch_bounds__(512, 4) void k_attn(
    const u16* __restrict__ qb, const u16* __restrict__ kb,
    const u16* __restrict__ vt, u16* __restrict__ ao) {
  __shared__ u16 lK[128 * 72];    // [key][d] bf16, stride 72
  __shared__ u16 lV[64 * 136];    // [d][key] f16, stride 136
  const int bh = blockIdx.y;
  const int q0 = blockIdx.x * 128;
  const int tid = threadIdx.x, wave = tid >> 6, lane = tid & 63;
  const int lrow = lane & 15, lq = lane >> 4;
  const int wq = wave * 16;

  // Q fragments (B-operand: n=q=lane&15, k=d=quad*8+j); q pre-scaled by CS in GEMM epilogue
  b8 qf[2];
#pragma unroll
  for (int ks = 0; ks < 2; ++ks)
    qf[ks] = *(const b8*)(qb + ((size_t)bh * 2048 + q0 + wq + lrow) * 64 + ks * 32 + lq * 8);

  float mr = -3.0e38f, lr = 0.f;
  f4 o[4] = {};   // O^T tiles [dt]: row=d=quad*4+r, col=q=lane&15

  const u16* kbase = kb + (size_t)bh * 2048 * 64;
  const u16* vbase = vt + (size_t)bh * 64 * 2048;

  for (int kt0 = 0; kt0 < 2048; kt0 += 128) {
#pragma unroll
    for (int s = 0; s < 2; ++s) {
      int ch = s * 512 + tid;
      int kr = ch >> 3, kc = ch & 7;    // K tile: 128 rows x 8 chunks
      *(uint4*)(lK + kr * 72 + kc * 8) =
          *(const uint4*)(kbase + (size_t)(kt0 + kr) * 64 + kc * 8);
      int vr = ch >> 4, vc = ch & 15;   // V tile: 64 rows x 16 chunks
      *(uint4*)(lV + vr * 136 + vc * 8) =
          *(const uint4*)(vbase + (size_t)vr * 2048 + kt0 + vc * 8);
    }
    __syncthreads();

    // ST = K·Q^T: st[kt], row=key=kt*16+quad*4+r, col=q=lane&15
    f4 st[8] = {};
#pragma unroll
    for (int ks = 0; ks < 2; ++ks)
#pragma unroll
      for (int kt = 0; kt < 8; ++kt) {
        b8 kf = *(const b8*)(lK + (kt * 16 + lrow) * 72 + ks * 32 + lq * 8);
        st[kt] = __builtin_amdgcn_mfma_f32_16x16x32_bf16(kf, qf[ks], st[kt], 0, 0, 0);
      }

    // online softmax (per-q stats: in-register over 8 f4 + 2 shuffles)
    f4 m4 = max4(max4(max4(st[0], st[1]), max4(st[2], st[3])),
                 max4(max4(st[4], st[5]), max4(st[6], st[7])));
    float mx = fmaxf(fmaxf(m4[0], m4[1]), fmaxf(m4[2], m4[3]));
    mx = fmaxf(mx, __shfl_xor(mx, 16, 64));
    mx = fmaxf(mx, __shfl_xor(mx, 32, 64));
    float mnew = fmaxf(mr, mx);
    float a = exp2f(mr - mnew);
    mr = mnew;
    h4 pf[8];
    f4 ps4 = {};
#pragma unroll
    for (int kt = 0; kt < 8; ++kt) {
      f4 e;
#pragma unroll
      for (int r = 0; r < 4; ++r) e[r] = exp2f(st[kt][r] - mnew);
      ps4 += e;
#pragma unroll
      for (int r = 0; r < 4; ++r) pf[kt][r] = (_Float16)e[r];
    }
    float ps = ps4[0] + ps4[1] + ps4[2] + ps4[3];
    ps += __shfl_xor(ps, 16, 64);
    ps += __shfl_xor(ps, 32, 64);
    lr = lr * a + ps;
#pragma unroll
    for (int dt = 0; dt < 4; ++dt) o[dt] *= a;

    // O^T += V^T · P^T  (K=16 f16 MFMA; P^T frags are st's C-layout regs, no LDS)
#pragma unroll
    for (int kt = 0; kt < 8; ++kt)
#pragma unroll
      for (int dt = 0; dt < 4; ++dt) {
        h4 va = *(const h4*)(lV + (dt * 16 + lrow) * 136 + kt * 16 + lq * 4);
        o[dt] = __builtin_amdgcn_mfma_f32_16x16x16f16(va, pf[kt], o[dt], 0, 0, 0);
      }
    __syncthreads();
  }

  const int bb = bh >> 4, h = bh & 15;
  float inv = 1.0f / lr;
  int q = q0 + wq + lrow;
#pragma unroll
  for (int dt = 0; dt < 4; ++dt) {
    union { u16 h2[4]; uint2 v; } r;
#pragma unroll
    for (int rr = 0; rr < 4; ++rr) r.h2[rr] = f2bf(o[dt][rr] * inv);
    *(uint2*)(ao + ((size_t)bb * 2048 + q) * 1024 + h * 64 + dt * 16 + lq * 4) = r.v;
  }
}

extern "C" void kernel_launch(void* const* d_in, const int* in_sizes, int n_in,
                              void* d_out, int out_size, void* d_ws, size_t ws_size,
                              hipStream_t stream) {
  const float* x      = (const float*)d_in[0];
  const float* w_qkv  = (const float*)d_in[1];
  const float* b_qkv  = (const float*)d_in[2];
  const float* q_w    = (const float*)d_in[3];
  const float* k_w    = (const float*)d_in[4];
  const float* w_proj = (const float*)d_in[5];
  const float* b_proj = (const float*)d_in[6];
  float* out = (float*)d_out;

  u16* xb   = (u16*)d_ws;          // 4096x1024 bf16
  u16* wqkT = xb + 4194304;        // 3072x1024 bf16
  u16* wpjT = wqkT + 3145728;      // 1024x1024 bf16
  u16* qb   = wpjT + 1048576;      // [BH][N][D] bf16 (CS-scaled)
  u16* kb   = qb + 4194304;        // [BH][N][D] bf16
  u16* vtb  = kb + 4194304;        // [BH][D][N] f16
  u16* ao   = xb;                  // attention out reuses xb

  k_convert_x<<<2048, 256, 0, stream>>>(x, xb);
  k_convert_wT<<<dim3(48, 16), 256, 0, stream>>>(w_qkv, wqkT, 3072, 1024);
  k_convert_wT<<<dim3(16, 16), 256, 0, stream>>>(w_proj, wpjT, 1024, 1024);
  k_gemm<0><<<dim3(24, 32), 256, 0, stream>>>(xb, wqkT, b_qkv, nullptr, qb, kb, vtb,
                                              q_w, k_w, 1024, 3072);
  k_attn<<<dim3(16, 32), 512, 0, stream>>>(qb, kb, vtb, ao);
  k_gemm<1><<<dim3(8, 32), 256, 0, stream>>>(ao, wpjT, b_proj, out, nullptr, nullptr, nullptr,
                                             nullptr, nullptr, 1024, 1024);
}